// Round 1
// baseline (446.872 us; speedup 1.0000x reference)
//
#include <hip/hip_runtime.h>

// DtN operator, M=64 grid, N=32 RHS, NB=252 boundary points.
// Strategy: one workgroup per RHS. Jacobi-preconditioned CG in fp64 on the
// interior 5-point operator; search direction p in LDS, everything else in
// registers. Flux + mean-subtract fused at the end.

#define MM 4096     // 64*64
#define NBP 252     // 4*64-4
#define NPT 8       // grid points per thread (512 threads * 8 = 4096)
#define BLK 512

static __device__ __forceinline__ double hm(double x, double y) {
    double d = x + y;
    return d == 0.0 ? 0.0 : 2.0 * x * y / d;
}

// block reduction over 512 threads (8 waves of 64)
static __device__ __forceinline__ double bred(double v, double* red) {
    #pragma unroll
    for (int off = 32; off > 0; off >>= 1) v += __shfl_down(v, off, 64);
    const int lane = threadIdx.x & 63, wid = threadIdx.x >> 6;
    if (lane == 0) red[wid] = v;
    __syncthreads();
    if (threadIdx.x < 64) {
        double s = (lane < 8) ? red[lane] : 0.0;
        #pragma unroll
        for (int off = 4; off > 0; off >>= 1) s += __shfl_down(s, off, 64);
        if (lane == 0) red[8] = s;
    }
    __syncthreads();
    return red[8];
}

__global__ __launch_bounds__(BLK, 1) void dtn_cg(const float* __restrict__ dbc,
                                                 const float* __restrict__ a,
                                                 float* __restrict__ out) {
    __shared__ double p[MM];
    __shared__ double red[12];
    const int t = threadIdx.x;
    const int n = blockIdx.x;
    const float* db = dbc + n * NBP;
    const double inv_h2 = 3969.0;   // (M-1)^2 = 63^2

    double u[NPT], r[NPT], z[NPT], ap[NPT];
    double cE[NPT], cW[NPT], cN[NPT], cS[NPT], dg[NPT], idg[NPT];

    // --- per-point stencil coefficients (registers) + Dirichlet embedding ---
    #pragma unroll
    for (int k = 0; k < NPT; ++k) {
        const int idx = t + (k << 9);
        const int i = idx >> 6, j = idx & 63;
        double e = 0, w = 0, nn = 0, s = 0, ig = 0;
        if (i > 0 && i < 63 && j > 0 && j < 63) {
            const double ac = (double)a[idx];
            e  = inv_h2 * hm(ac, (double)a[idx + 1]);
            w  = inv_h2 * hm((double)a[idx - 1], ac);
            nn = inv_h2 * hm((double)a[idx - 64], ac);
            s  = inv_h2 * hm(ac, (double)a[idx + 64]);
            ig = 1.0 / (e + w + nn + s);
        }
        cE[k] = e; cW[k] = w; cN[k] = nn; cS[k] = s;
        dg[k] = e + w + nn + s; idg[k] = ig;

        // clockwise boundary embedding (top, right, bottom rev, left rev)
        double uv = 0.0;
        if (i == 0 && j <= 62)       uv = (double)db[j];
        else if (j == 63 && i <= 62) uv = (double)db[63 + i];
        else if (i == 63 && j >= 1)  uv = (double)db[189 - j];
        else if (j == 0 && i >= 1)   uv = (double)db[252 - i];
        u[k] = uv;
        p[idx] = uv;                 // stage u0 for initial residual
    }
    __syncthreads();

    // --- r0 = -A u0 on interior (f_int = 0, u0_int = 0): boundary coupling ---
    double rz_loc = 0.0;
    #pragma unroll
    for (int k = 0; k < NPT; ++k) {
        const int idx = t + (k << 9);
        double rv = 0.0;
        if (idg[k] != 0.0)
            rv = cW[k] * p[idx - 1] + cE[k] * p[idx + 1] +
                 cN[k] * p[idx - 64] + cS[k] * p[idx + 64];
        r[k] = rv;
        z[k] = idg[k] * rv;
        rz_loc += rv * z[k];
    }
    __syncthreads();                 // all reads of p(=u0) done before overwrite
    #pragma unroll
    for (int k = 0; k < NPT; ++k) p[t + (k << 9)] = z[k];

    double rz = bred(rz_loc, red);   // bred's first sync covers the p writes
    const double rz0 = rz;
    const double stop = rz0 * 1e-14;

    if (rz0 > 0.0) {
        for (int it = 0; it < 500; ++it) {
            // Ap (registers) + <p,Ap>
            double pap_loc = 0.0;
            #pragma unroll
            for (int k = 0; k < NPT; ++k) {
                const int idx = t + (k << 9);
                double apv = 0.0;
                if (idg[k] != 0.0) {
                    apv = dg[k] * p[idx] -
                          (cW[k] * p[idx - 1] + cE[k] * p[idx + 1] +
                           cN[k] * p[idx - 64] + cS[k] * p[idx + 64]);
                    pap_loc += p[idx] * apv;
                }
                ap[k] = apv;
            }
            const double pap = bred(pap_loc, red);
            if (!(pap > 0.0)) break;
            const double alpha = rz / pap;

            double rzn_loc = 0.0;
            #pragma unroll
            for (int k = 0; k < NPT; ++k) {
                const int idx = t + (k << 9);
                u[k] += alpha * p[idx];
                r[k] -= alpha * ap[k];
                z[k] = idg[k] * r[k];
                rzn_loc += r[k] * z[k];
            }
            const double rzn = bred(rzn_loc, red);
            const double beta = rzn / rz;
            rz = rzn;
            if (rzn <= stop) break;
            #pragma unroll
            for (int k = 0; k < NPT; ++k) {
                const int idx = t + (k << 9);
                p[idx] = z[k] + beta * p[idx];
            }
            __syncthreads();
        }
    }

    // --- stage solved u into LDS for flux ---
    #pragma unroll
    for (int k = 0; k < NPT; ++k) p[t + (k << 9)] = u[k];
    __syncthreads();

    // --- Neumann flux (clockwise: tl, top, tr, right, br, bottom rev, bl, left rev) ---
    double v = 0.0;
    if (t < NBP) {
        const double Hi = 63.0;
        if (t == 0)        v = (double)a[0]    * 0.5 * ((p[0]-p[64]) + (p[0]-p[1])) * Hi;
        else if (t <= 62)  v = (double)a[t]    * (p[t] - p[64 + t]) * Hi;
        else if (t == 63)  v = (double)a[63]   * 0.5 * ((p[63]-p[127]) + (p[63]-p[62])) * Hi;
        else if (t <= 125) { const int i = t - 63;
                             v = (double)a[(i<<6)+63] * (p[(i<<6)+63] - p[(i<<6)+62]) * Hi; }
        else if (t == 126) v = (double)a[4095] * 0.5 * ((p[4095]-p[4031]) + (p[4095]-p[4094])) * Hi;
        else if (t <= 188) { const int j = 189 - t;
                             v = (double)a[4032+j] * (p[4032+j] - p[3968+j]) * Hi; }
        else if (t == 189) v = (double)a[4032] * 0.5 * ((p[4032]-p[3968]) + (p[4032]-p[4033])) * Hi;
        else               { const int i = 252 - t;
                             v = (double)a[i<<6] * (p[i<<6] - p[(i<<6)+1]) * Hi; }
    }
    const double tot = bred(v, red);
    if (t < NBP) out[n * NBP + t] = (float)(v - tot * (1.0 / 252.0));
}

extern "C" void kernel_launch(void* const* d_in, const int* in_sizes, int n_in,
                              void* d_out, int out_size, void* d_ws, size_t ws_size,
                              hipStream_t stream) {
    const float* dbc = (const float*)d_in[0];   // (32, 252)
    const float* a   = (const float*)d_in[1];   // (64, 64)
    float* out = (float*)d_out;                 // (32, 252)
    dtn_cg<<<dim3(32), dim3(BLK), 0, stream>>>(dbc, a, out);
}

// Round 2
// 287.128 us; speedup vs baseline: 1.5564x; 1.5564x over previous
//
#include <hip/hip_runtime.h>

// DtN operator, M=64, N=32 RHS. One workgroup per RHS.
// Chebyshev(deg-8)-preconditioned CG in fp64 on the symmetrically scaled
// interior operator B = D^{-1/2} A D^{-1/2} (unit diagonal, spectrum in (0,2)).
// Row-contiguous ownership: thread t owns row t>>3, cols ((t&7)*8)..+7.

#define BLK 512
#define NBP 252
#define DEG 8        // matvecs per preconditioner apply = DEG-1
#define MAXOUT 150

static __device__ __forceinline__ double hm(double x, double y) {
    double d = x + y;
    return d == 0.0 ? 0.0 : 2.0 * x * y / d;
}

// one-barrier block reduction: wave partials -> LDS -> replicated sum
static __device__ __forceinline__ double bred(double v, double* slot) {
    #pragma unroll
    for (int off = 32; off > 0; off >>= 1) v += __shfl_down(v, off, 64);
    if ((threadIdx.x & 63) == 0) slot[threadIdx.x >> 6] = v;
    __syncthreads();
    double s = 0.0;
    #pragma unroll
    for (int w = 0; w < 8; ++w) s += slot[w];
    return s;
}

// clockwise Dirichlet embedding (top, right, bottom rev, left rev)
static __device__ __forceinline__ double embed(const float* db, int i, int j) {
    if (i == 0 && j <= 62) return (double)db[j];
    if (j == 63 && i <= 62) return (double)db[63 + i];
    if (i == 63 && j >= 1)  return (double)db[189 - j];
    return (double)db[252 - i];   // j==0, i>=1
}

__global__ __launch_bounds__(BLK, 1) void dtn_cheb(const float* __restrict__ dbc,
                                                   const float* __restrict__ a,
                                                   float* __restrict__ out) {
    __shared__ double P[4096];
    __shared__ double Z0[4096];
    __shared__ double Z1[4096];
    __shared__ double redA[8], redB[8];

    const int t = threadIdx.x;
    const int row = t >> 3;
    const int cb  = (t & 7) << 3;
    const int base = (row << 6) + cb;
    const float* db = dbc + blockIdx.x * NBP;
    const bool irow = (row >= 1 && row <= 62);

    double cE[8], cW[8], cN[8], cS[8], sD[8];
    double y[8], r[8], z[8], dv[8], pw[8];

    // ---- init: raw harmonic-mean coefficients (h^-2 cancels), scale, u0 ----
    #pragma unroll
    for (int q = 0; q < 8; ++q) {
        const int idx = base + q;
        const int i = row, j = cb + q;
        double e = 0, w = 0, nn = 0, ss = 0, sv = 0;
        if (i > 0 && i < 63 && j > 0 && j < 63) {
            const double ac = (double)a[idx];
            e  = hm(ac, (double)a[idx + 1]);
            w  = hm((double)a[idx - 1], ac);
            nn = hm((double)a[idx - 64], ac);
            ss = hm(ac, (double)a[idx + 64]);
            sv = 1.0 / sqrt(e + w + nn + ss);
        }
        cE[q] = e; cW[q] = w; cN[q] = nn; cS[q] = ss; sD[q] = sv;
        double uv = 0.0;
        if (i == 0 || i == 63 || j == 0 || j == 63) uv = embed(db, i, j);
        P[idx]  = uv;    // u0 (boundary data, interior 0)
        Z0[idx] = sv;    // stage s for neighbor access
    }
    __syncthreads();

    // ---- g = s .* (A_raw u0) on interior; build scaled coefficients ----
    double g[8];
    #pragma unroll
    for (int q = 0; q < 8; ++q) g[q] = 0.0;
    if (irow) {
        #pragma unroll
        for (int q = 0; q < 8; ++q) {
            const int idx = base + q;
            const double uN = P[idx - 64], uS = P[idx + 64];
            const double uW = P[idx - 1],  uE = P[idx + 1];
            g[q] = sD[q] * (cE[q] * uE + cW[q] * uW + cN[q] * uN + cS[q] * uS);
            const double sN = Z0[idx - 64], sS = Z0[idx + 64];
            const double sW = Z0[idx - 1],  sE = Z0[idx + 1];
            cE[q] *= sD[q] * sE; cW[q] *= sD[q] * sW;
            cN[q] *= sD[q] * sN; cS[q] *= sD[q] * sS;
        }
    } else {
        #pragma unroll
        for (int q = 0; q < 8; ++q) { cE[q] = cW[q] = cN[q] = cS[q] = 0.0; }
    }
    __syncthreads();   // all reads of s (Z0) complete before Z0 is reused

    // ---- Chebyshev preconditioner: z ~= B^{-1} r, spectrum in [0.02, 2.0] ----
    const double thet = 0.5 * (2.0 + 0.02);
    const double delt = 0.5 * (2.0 - 0.02);
    const double sig  = thet / delt;
    const double invthet = 1.0 / thet;

    auto cheb = [&](const double* rr, double* zz) {
        double rho = 1.0 / sig;
        #pragma unroll
        for (int q = 0; q < 8; ++q) { dv[q] = rr[q] * invthet; zz[q] = dv[q]; Z1[base + q] = zz[q]; }
        int cur = 1;
        for (int k = 2; k <= DEG; ++k) {
            __syncthreads();   // zz writes visible; previous buffer reads done
            double* Zc = cur ? Z1 : Z0;
            double* Za = cur ? Z0 : Z1;
            double res[8];
            if (irow) {
                #pragma unroll
                for (int q = 0; q < 8; ++q) {
                    const int idx = base + q;
                    const double vN = Zc[idx - 64], vS = Zc[idx + 64];
                    const double vW = (q == 0) ? Zc[idx - 1] : zz[q - 1];
                    const double vE = (q == 7) ? Zc[idx + 1] : zz[q + 1];
                    const double Bz = zz[q] - (cE[q] * vE + cW[q] * vW + cN[q] * vN + cS[q] * vS);
                    res[q] = rr[q] - Bz;
                }
            } else {
                #pragma unroll
                for (int q = 0; q < 8; ++q) res[q] = 0.0;
            }
            const double rho1 = 1.0 / (2.0 * sig - rho);
            const double c1 = rho1 * rho, c2 = 2.0 * rho1 / delt;
            #pragma unroll
            for (int q = 0; q < 8; ++q) { dv[q] = c1 * dv[q] + c2 * res[q]; zz[q] += dv[q]; Za[base + q] = zz[q]; }
            rho = rho1; cur ^= 1;
        }
    };

    // ---- PCG on B y = g ----
    #pragma unroll
    for (int q = 0; q < 8; ++q) { y[q] = 0.0; r[q] = g[q]; }

    cheb(r, z);
    double rz_loc = 0.0;
    #pragma unroll
    for (int q = 0; q < 8; ++q) { pw[q] = z[q]; P[base + q] = z[q]; rz_loc += r[q] * z[q]; }
    double rz = bred(rz_loc, redB);
    const double stop = rz * 1e-13;

    for (int ot = 0; ot < MAXOUT && rz > stop; ++ot) {
        __syncthreads();   // P (p-vector) writes visible for stencil
        double w[8];
        double pap_loc = 0.0;
        if (irow) {
            #pragma unroll
            for (int q = 0; q < 8; ++q) {
                const int idx = base + q;
                const double vN = P[idx - 64], vS = P[idx + 64];
                const double vW = (q == 0) ? P[idx - 1] : pw[q - 1];
                const double vE = (q == 7) ? P[idx + 1] : pw[q + 1];
                w[q] = pw[q] - (cE[q] * vE + cW[q] * vW + cN[q] * vN + cS[q] * vS);
                pap_loc += pw[q] * w[q];
            }
        } else {
            #pragma unroll
            for (int q = 0; q < 8; ++q) w[q] = 0.0;
        }
        const double pap = bred(pap_loc, redA);
        if (!(pap > 0.0)) break;
        const double alpha = rz / pap;
        #pragma unroll
        for (int q = 0; q < 8; ++q) { y[q] += alpha * pw[q]; r[q] -= alpha * w[q]; }
        cheb(r, z);
        double rzn_loc = 0.0;
        #pragma unroll
        for (int q = 0; q < 8; ++q) rzn_loc += r[q] * z[q];
        const double rzn = bred(rzn_loc, redB);
        const double beta = rzn / rz;
        rz = rzn;
        if (rz > stop) {
            #pragma unroll
            for (int q = 0; q < 8; ++q) { pw[q] = z[q] + beta * pw[q]; P[base + q] = pw[q]; }
        }
    }

    // ---- final u = s .* y (interior), dbc on boundary; stage in P ----
    __syncthreads();
    #pragma unroll
    for (int q = 0; q < 8; ++q) {
        const int idx = base + q;
        const int i = row, j = cb + q;
        double uv;
        if (i == 0 || i == 63 || j == 0 || j == 63) uv = embed(db, i, j);
        else uv = sD[q] * y[q];
        P[idx] = uv;
    }
    __syncthreads();

    // ---- Neumann flux (clockwise) + de-mean ----
    double v = 0.0;
    if (t < NBP) {
        const double Hi = 63.0;
        if (t == 0)        v = (double)a[0]    * 0.5 * ((P[0]-P[64]) + (P[0]-P[1])) * Hi;
        else if (t <= 62)  v = (double)a[t]    * (P[t] - P[64 + t]) * Hi;
        else if (t == 63)  v = (double)a[63]   * 0.5 * ((P[63]-P[127]) + (P[63]-P[62])) * Hi;
        else if (t <= 125) { const int i = t - 63;
                             v = (double)a[(i<<6)+63] * (P[(i<<6)+63] - P[(i<<6)+62]) * Hi; }
        else if (t == 126) v = (double)a[4095] * 0.5 * ((P[4095]-P[4031]) + (P[4095]-P[4094])) * Hi;
        else if (t <= 188) { const int j = 189 - t;
                             v = (double)a[4032+j] * (P[4032+j] - P[3968+j]) * Hi; }
        else if (t == 189) v = (double)a[4032] * 0.5 * ((P[4032]-P[3968]) + (P[4032]-P[4033])) * Hi;
        else               { const int i = 252 - t;
                             v = (double)a[i<<6] * (P[i<<6] - P[(i<<6)+1]) * Hi; }
    }
    const double tot = bred(v, redA);
    if (t < NBP) out[blockIdx.x * NBP + t] = (float)(v - tot * (1.0 / 252.0));
}

extern "C" void kernel_launch(void* const* d_in, const int* in_sizes, int n_in,
                              void* d_out, int out_size, void* d_ws, size_t ws_size,
                              hipStream_t stream) {
    const float* dbc = (const float*)d_in[0];   // (32, 252)
    const float* a   = (const float*)d_in[1];   // (64, 64)
    float* out = (float*)d_out;                 // (32, 252)
    dtn_cheb<<<dim3(32), dim3(BLK), 0, stream>>>(dbc, a, out);
}